// Round 4
// baseline (265.100 us; speedup 1.0000x reference)
//
#include <hip/hip_runtime.h>
#include <math.h>

#define MIN_T    0.01f
#define MAX_T    0.5f
#define LESION_T 0.3f

constexpr int NB       = 16;
constexpr int DIM      = 128;
constexpr int PLANE_F4 = DIM * DIM / 4;        // 4096 float4 per plane
constexpr int VOX      = DIM * DIM * DIM;      // 2,097,152
constexpr int THREADS  = 256;
constexpr int HWBLKS   = PLANE_F4 / THREADS;   // 16 row-slabs (8 rows each)
constexpr int DSEGS    = 8;                    // d-axis segments
constexpr int DPS      = DIM / DSEGS;          // 16 planes per segment
constexpr int NACC     = 8;
constexpr int TOTAL_BLOCKS = DSEGS * HWBLKS * NB;   // 2048

// ws layout: float acc[NB][NACC] (512 B) | unsigned counter (at +512)
// acc per batch: 0 cnt>MIN  1 cnt>MAX  2 sum|dD|  3 sum|dH|  4 sum|dW|
//                5 sum s*mask  6 sum s^2*mask  7 cnt>LESION
__global__ __launch_bounds__(THREADS)
void fused_kernel(const float* __restrict__ pred, float* __restrict__ acc,
                  unsigned* __restrict__ counter, float* __restrict__ out)
{
    const int seg   = blockIdx.x;
    const int hwblk = blockIdx.y;
    const int b     = blockIdx.z;
    const int tid   = (int)threadIdx.x;

    const float4* __restrict__ s4 =
        reinterpret_cast<const float4*>(pred + (size_t)b * VOX);

    const int  h    = hwblk * 8 + (tid >> 5);
    const bool do_h = (h < DIM - 1);
    const bool do_w = ((tid & 31) != 31);

    const int d0    = seg * DPS;
    const int npair = (seg == DSEGS - 1) ? (DPS - 1) : DPS;
    const int last  = d0 + npair;

    float cnt_min = 0.f, cnt_max = 0.f, sum_d = 0.f, sum_h = 0.f,
          sum_w = 0.f, sm = 0.f, sm2 = 0.f, les = 0.f;

    auto process = [&](const float4& v, const float4& vh) {
        const float xs[4] = { v.x, v.y, v.z, v.w };
        #pragma unroll
        for (int j = 0; j < 4; ++j) {
            const float x    = xs[j];
            const bool  gmin = (x > MIN_T);
            const float xm   = gmin ? x : 0.0f;
            cnt_min += gmin ? 1.0f : 0.0f;
            sm      += xm;
            sm2      = fmaf(xm, x, sm2);
            cnt_max += (x > MAX_T)    ? 1.0f : 0.0f;
            les     += (x > LESION_T) ? 1.0f : 0.0f;
        }
        sum_w += fabsf(v.y - v.x) + fabsf(v.z - v.y) + fabsf(v.w - v.z);
        const float nx = __shfl_down(v.x, 1, 64);
        if (do_w) sum_w += fabsf(nx - v.w);
        if (do_h) sum_h += fabsf(vh.x - v.x) + fabsf(vh.y - v.y)
                         + fabsf(vh.z - v.z) + fabsf(vh.w - v.w);
    };

    const float4 z4 = { 0.f, 0.f, 0.f, 0.f };
    const size_t off = (size_t)hwblk * THREADS + tid;
    size_t base = (size_t)d0 * PLANE_F4 + off;
    const size_t lastbase = (size_t)last * PLANE_F4 + off;

    // 2-deep software pipeline over planes
    float4 v0 = s4[base];
    float4 h0 = do_h ? s4[base + 32] : z4;
    float4 v1 = s4[base + PLANE_F4];
    float4 h1 = do_h ? s4[base + PLANE_F4 + 32] : z4;
    size_t pbase = base + 2 * (size_t)PLANE_F4;

    for (int d = d0; d < d0 + npair; ++d) {
        const size_t pf = (pbase < lastbase) ? pbase : lastbase;
        const float4 v2 = s4[pf];
        const float4 h2 = do_h ? s4[pf + 32] : z4;
        process(v0, h0);
        sum_d += fabsf(v1.x - v0.x) + fabsf(v1.y - v0.y)
               + fabsf(v1.z - v0.z) + fabsf(v1.w - v0.w);
        v0 = v1; h0 = h1; v1 = v2; h1 = h2;
        pbase += PLANE_F4;
    }
    if (seg == DSEGS - 1)             // plane 127 stats (no outgoing d-pair)
        process(v0, h0);

    // wave shuffle reduction, then LDS across the 4 waves
    float vals[NACC] = { cnt_min, cnt_max, sum_d, sum_h, sum_w, sm, sm2, les };
    #pragma unroll
    for (int vi = 0; vi < NACC; ++vi) {
        float x = vals[vi];
        #pragma unroll
        for (int offs = 32; offs > 0; offs >>= 1)
            x += __shfl_down(x, offs, 64);
        vals[vi] = x;
    }

    __shared__ float smem[4][NACC];
    const int wave = tid >> 6;
    const int lane = tid & 63;
    if (lane == 0) {
        #pragma unroll
        for (int vi = 0; vi < NACC; ++vi) smem[wave][vi] = vals[vi];
    }
    __syncthreads();

    __shared__ unsigned lastflag;
    if (tid < NACC) {
        const float t = smem[0][tid] + smem[1][tid] +
                        smem[2][tid] + smem[3][tid];
        atomicAdd(&acc[b * NACC + tid], t);     // device-scope, cross-XCD safe
    }
    __syncthreads();                            // all 8 atomics issued...
    if (tid == 0) {
        __threadfence();                        // ...and visible before ticket
        const unsigned old = atomicAdd(counter, 1u);
        lastflag = (old == TOTAL_BLOCKS - 1) ? 1u : 0u;
    }
    __syncthreads();
    if (!lastflag) return;

    // ---- last block overall: finalize ----
    __shared__ float sacc[NB * NACC];
    __shared__ float lss[NB];
    if (tid < NB * NACC)
        sacc[tid] = atomicAdd(&acc[tid], 0.0f); // atomic read: coherent w/ adds
    __syncthreads();

    if (tid < NB) {
        const float* a = &sacc[tid * NACC];
        const double cnt    = a[0];
        const double cntmax = a[1];
        const double sd     = a[2];
        const double sh     = a[3];
        const double sw     = a[4];
        const double smv    = a[5];
        const double sm2v   = a[6];
        const double lescnt = a[7];

        const double inv_vox = 1.0 / (double)VOX;
        const double act  = cnt    * inv_vox;
        const double high = cntmax * inv_vox;

        double loss = fmax(0.005 - act, 0.0) * 15.0       // W_MIN
                    + fmax(high - 0.03, 0.0) * 5.0;       // W_MAX

        const double grad_den = 127.0 * 128.0 * 128.0;
        const double avg_grad = (sd + sh + sw) / (3.0 * grad_den);
        if (lescnt > 0.5)
            loss += fmin(avg_grad, 1.0) * 5.0;            // W_CONT

        const double cnt_safe = fmax(cnt, 1.0);
        const double m  = smv / cnt_safe;
        double sq = sm2v - 2.0 * m * smv + m * m * cnt;
        if (sq < 0.0) sq = 0.0;

        const bool gate = (act > 0.001) && (cnt > 1.0);
        if (gate) {
            const double var     = sq / fmax(cnt - 1.0, 1.0);
            const double rel_std = sqrt(var) / (m + 1e-6);
            loss += exp(-5.0 * rel_std) * 7.0;            // W_SIZE
        }
        lss[tid] = (float)loss;
    }
    __syncthreads();
    if (tid == 0) {
        float s = 0.f;
        #pragma unroll
        for (int i = 0; i < NB; ++i) s += lss[i];
        out[0] = s / (float)NB;
    }
}

extern "C" void kernel_launch(void* const* d_in, const int* in_sizes, int n_in,
                              void* d_out, int out_size, void* d_ws, size_t ws_size,
                              hipStream_t stream)
{
    const float* pred = (const float*)d_in[0];
    float* out        = (float*)d_out;
    float* acc        = (float*)d_ws;
    unsigned* counter = (unsigned*)((char*)d_ws + NB * NACC * sizeof(float));

    // zero accumulators + completion counter (ws is poisoned before each call)
    hipMemsetAsync(d_ws, 0, NB * NACC * sizeof(float) + sizeof(unsigned), stream);

    dim3 grid(DSEGS, HWBLKS, NB);
    fused_kernel<<<grid, THREADS, 0, stream>>>(pred, acc, counter, out);
}

// Round 5
// 197.718 us; speedup vs baseline: 1.3408x; 1.3408x over previous
//
#include <hip/hip_runtime.h>
#include <math.h>

#define MIN_T    0.01f
#define MAX_T    0.5f
#define LESION_T 0.3f

constexpr int NB       = 16;
constexpr int DIM      = 128;
constexpr int PLANE_F4 = DIM * DIM / 4;        // 4096 float4 per plane
constexpr int VOX      = DIM * DIM * DIM;      // 2,097,152
constexpr int THREADS  = 256;
constexpr int HWBLKS   = PLANE_F4 / THREADS;   // 16 row-slabs (8 rows each)
constexpr int DSEGS    = 8;                    // d-axis segments
constexpr int DPS      = DIM / DSEGS;          // 16 planes per segment
constexpr int NACC     = 8;

struct Acc {
    float cnt_min = 0.f, cnt_max = 0.f, sum_d = 0.f, sum_h = 0.f,
          sum_w = 0.f, sm = 0.f, sm2 = 0.f, les = 0.f;
};

__device__ __forceinline__ void stats(const float4 v, const float4 vh,
                                      bool do_h, bool do_w, Acc& a)
{
    const float xs[4] = { v.x, v.y, v.z, v.w };
    #pragma unroll
    for (int j = 0; j < 4; ++j) {
        const float x    = xs[j];
        const bool  gmin = (x > MIN_T);
        const float xm   = gmin ? x : 0.0f;
        a.cnt_min += gmin ? 1.0f : 0.0f;
        a.sm      += xm;
        a.sm2      = fmaf(xm, x, a.sm2);
        a.cnt_max += (x > MAX_T)    ? 1.0f : 0.0f;
        a.les     += (x > LESION_T) ? 1.0f : 0.0f;
    }
    a.sum_w += fabsf(v.y - v.x) + fabsf(v.z - v.y) + fabsf(v.w - v.z);
    const float nx = __shfl_down(v.x, 1, 64);    // next float4's .x, same row
    if (do_w) a.sum_w += fabsf(nx - v.w);
    if (do_h) a.sum_h += fabsf(vh.x - v.x) + fabsf(vh.y - v.y)
                       + fabsf(vh.z - v.z) + fabsf(vh.w - v.w);
}

// Processes NPAIR d-pairs starting at plane base; stats for the first NPAIR
// planes (plus the final plane if LAST). Fully unrolled: all loads visible
// to the scheduler for deep pipelining.
template<int NPAIR, bool LAST>
__device__ __forceinline__ void seg_body(const float4* __restrict__ s4,
                                         size_t base, int hoff,
                                         bool do_h, bool do_w, Acc& a)
{
    float4 v0 = s4[base];
    float4 h0 = s4[base + hoff];
    #pragma unroll
    for (int k = 0; k < NPAIR; ++k) {
        const size_t nb = base + (size_t)(k + 1) * PLANE_F4;
        const float4 v1 = s4[nb];
        const float4 h1 = s4[nb + hoff];
        stats(v0, h0, do_h, do_w, a);
        a.sum_d += fabsf(v1.x - v0.x) + fabsf(v1.y - v0.y)
                 + fabsf(v1.z - v0.z) + fabsf(v1.w - v0.w);
        v0 = v1; h0 = h1;
    }
    if (LAST) stats(v0, h0, do_h, do_w, a);      // plane 127, no outgoing pair
}

// Accumulator layout per batch (doubles):
// 0 cnt>MIN  1 cnt>MAX  2 sum|dD|  3 sum|dH|  4 sum|dW|
// 5 sum s*mask  6 sum s^2*mask  7 cnt>LESION
__global__ __launch_bounds__(THREADS)
void partial_kernel(const float* __restrict__ pred, double* __restrict__ acc)
{
    const int seg   = blockIdx.x;
    const int hwblk = blockIdx.y;
    const int b     = blockIdx.z;
    const int tid   = (int)threadIdx.x;

    const float4* __restrict__ s4 =
        reinterpret_cast<const float4*>(pred + (size_t)b * VOX);

    // thread owns float4 at (h = hwblk*8 + tid/32, w4 = tid%32) on each plane
    const int  h    = hwblk * 8 + (tid >> 5);
    const bool do_h = (h < DIM - 1);
    const bool do_w = ((tid & 31) != 31);
    const int  hoff = do_h ? 32 : 0;             // clamped neighbor offset

    const size_t base = (size_t)(seg * DPS) * PLANE_F4
                      + (size_t)hwblk * THREADS + tid;

    Acc a;
    if (seg != DSEGS - 1)
        seg_body<DPS, false>(s4, base, hoff, do_h, do_w, a);   // 16 pairs
    else
        seg_body<DPS - 1, true>(s4, base, hoff, do_h, do_w, a); // 15 + plane 127

    // wave (64-lane) shuffle reduction, then LDS across the 4 waves
    float vals[NACC] = { a.cnt_min, a.cnt_max, a.sum_d, a.sum_h,
                         a.sum_w, a.sm, a.sm2, a.les };
    #pragma unroll
    for (int vi = 0; vi < NACC; ++vi) {
        float x = vals[vi];
        #pragma unroll
        for (int offs = 32; offs > 0; offs >>= 1)
            x += __shfl_down(x, offs, 64);
        vals[vi] = x;
    }

    __shared__ float smem[4][NACC];
    const int wave = tid >> 6;
    const int lane = tid & 63;
    if (lane == 0) {
        #pragma unroll
        for (int vi = 0; vi < NACC; ++vi) smem[wave][vi] = vals[vi];
    }
    __syncthreads();
    if (tid < NACC) {
        const float t = smem[0][tid] + smem[1][tid] +
                        smem[2][tid] + smem[3][tid];
        atomicAdd(&acc[(size_t)b * NACC + tid], (double)t);
    }
}

__global__ __launch_bounds__(64)
void finalize_kernel(const double* __restrict__ acc, float* __restrict__ out)
{
    float l = 0.0f;
    if (threadIdx.x < NB) {
        const double* a = acc + (size_t)threadIdx.x * NACC;
        const double cnt    = a[0];
        const double cntmax = a[1];
        const double sd     = a[2];
        const double sh     = a[3];
        const double sw     = a[4];
        const double sm     = a[5];
        const double sm2    = a[6];
        const double les    = a[7];

        const double inv_vox = 1.0 / (double)VOX;
        const double act  = cnt    * inv_vox;
        const double high = cntmax * inv_vox;

        double loss = fmax(0.005 - act, 0.0) * 15.0      // W_MIN
                    + fmax(high - 0.03, 0.0) * 5.0;      // W_MAX

        const double grad_den = 127.0 * 128.0 * 128.0;   // diff-array size
        const double avg_grad = (sd + sh + sw) / (3.0 * grad_den);
        if (les > 0.5)
            loss += fmin(avg_grad, 1.0) * 5.0;           // W_CONT

        const double cnt_safe = fmax(cnt, 1.0);
        const double m  = sm / cnt_safe;
        double sq = sm2 - 2.0 * m * sm + m * m * cnt;
        if (sq < 0.0) sq = 0.0;

        const bool gate = (act > 0.001) && (cnt > 1.0);
        if (gate) {
            const double var     = sq / fmax(cnt - 1.0, 1.0);
            const double rel_std = sqrt(var) / (m + 1e-6);
            loss += exp(-5.0 * rel_std) * 7.0;           // W_SIZE
        }
        l = (float)loss;
    }
    #pragma unroll
    for (int offs = 32; offs > 0; offs >>= 1)
        l += __shfl_down(l, offs, 64);
    if (threadIdx.x == 0)
        out[0] = l / (float)NB;
}

extern "C" void kernel_launch(void* const* d_in, const int* in_sizes, int n_in,
                              void* d_out, int out_size, void* d_ws, size_t ws_size,
                              hipStream_t stream)
{
    const float* pred = (const float*)d_in[0];
    float* out        = (float*)d_out;
    double* acc       = (double*)d_ws;

    hipMemsetAsync(d_ws, 0, (size_t)NB * NACC * sizeof(double), stream);

    dim3 grid(DSEGS, HWBLKS, NB);
    partial_kernel<<<grid, THREADS, 0, stream>>>(pred, acc);
    finalize_kernel<<<1, 64, 0, stream>>>(acc, out);
}

// Round 6
// 197.141 us; speedup vs baseline: 1.3447x; 1.0029x over previous
//
#include <hip/hip_runtime.h>
#include <math.h>

#define MIN_T    0.01f
#define MAX_T    0.5f
#define LESION_T 0.3f

constexpr int NB       = 16;
constexpr int DIM      = 128;
constexpr int PLANE_F4 = DIM * DIM / 4;        // 4096 float4 per plane
constexpr int VOX      = DIM * DIM * DIM;      // 2,097,152
constexpr int THREADS  = 256;
constexpr int HWBLKS   = PLANE_F4 / THREADS;   // 16 row-slabs (8 rows each)
constexpr int DSEGS    = 16;                   // d-axis segments
constexpr int DPS      = DIM / DSEGS;          // 8 planes per segment
constexpr int NACC     = 8;
// slot = (b<<8) | (seg<<4) | hwblk ; 4096 slots x 8 floats = 128 KB in ws
constexpr int NSLOTS   = NB * DSEGS * HWBLKS;

struct Acc {
    float cnt_min = 0.f, cnt_max = 0.f, sum_d = 0.f, sum_h = 0.f,
          sum_w = 0.f, sm = 0.f, sm2 = 0.f, les = 0.f;
};

__device__ __forceinline__ void stats(const float4 v, const float4 vh,
                                      bool do_h, bool do_w, Acc& a)
{
    const float xs[4] = { v.x, v.y, v.z, v.w };
    #pragma unroll
    for (int j = 0; j < 4; ++j) {
        const float x    = xs[j];
        const bool  gmin = (x > MIN_T);
        const float xm   = gmin ? x : 0.0f;
        a.cnt_min += gmin ? 1.0f : 0.0f;
        a.sm      += xm;
        a.sm2      = fmaf(xm, x, a.sm2);
        a.cnt_max += (x > MAX_T)    ? 1.0f : 0.0f;
        a.les     += (x > LESION_T) ? 1.0f : 0.0f;
    }
    a.sum_w += fabsf(v.y - v.x) + fabsf(v.z - v.y) + fabsf(v.w - v.z);
    const float nx = __shfl_down(v.x, 1, 64);    // next float4's .x, same row
    if (do_w) a.sum_w += fabsf(nx - v.w);
    if (do_h) a.sum_h += fabsf(vh.x - v.x) + fabsf(vh.y - v.y)
                       + fabsf(vh.z - v.z) + fabsf(vh.w - v.w);
}

// NPAIR d-pairs from plane base; stats for first NPAIR planes (+ final if LAST).
template<int NPAIR, bool LAST>
__device__ __forceinline__ void seg_body(const float4* __restrict__ s4,
                                         size_t base, int hoff,
                                         bool do_h, bool do_w, Acc& a)
{
    float4 v0 = s4[base];
    float4 h0 = s4[base + hoff];
    #pragma unroll
    for (int k = 0; k < NPAIR; ++k) {
        const size_t nb = base + (size_t)(k + 1) * PLANE_F4;
        const float4 v1 = s4[nb];
        const float4 h1 = s4[nb + hoff];
        stats(v0, h0, do_h, do_w, a);
        a.sum_d += fabsf(v1.x - v0.x) + fabsf(v1.y - v0.y)
                 + fabsf(v1.z - v0.z) + fabsf(v1.w - v0.w);
        v0 = v1; h0 = h1;
    }
    if (LAST) stats(v0, h0, do_h, do_w, a);      // plane 127, no outgoing pair
}

// Per-slot accumulators (floats):
// 0 cnt>MIN  1 cnt>MAX  2 sum|dD|  3 sum|dH|  4 sum|dW|
// 5 sum s*mask  6 sum s^2*mask  7 cnt>LESION
__global__ __launch_bounds__(THREADS)
void partial_kernel(const float* __restrict__ pred, float* __restrict__ pacc)
{
    const int seg   = blockIdx.x;
    const int hwblk = blockIdx.y;
    const int b     = blockIdx.z;
    const int tid   = (int)threadIdx.x;

    const float4* __restrict__ s4 =
        reinterpret_cast<const float4*>(pred + (size_t)b * VOX);

    // thread owns float4 at (h = hwblk*8 + tid/32, w4 = tid%32) on each plane
    const int  h    = hwblk * 8 + (tid >> 5);
    const bool do_h = (h < DIM - 1);
    const bool do_w = ((tid & 31) != 31);
    const int  hoff = do_h ? 32 : 0;             // clamped neighbor offset

    const size_t base = (size_t)(seg * DPS) * PLANE_F4
                      + (size_t)hwblk * THREADS + tid;

    Acc a;
    if (seg != DSEGS - 1)
        seg_body<DPS, false>(s4, base, hoff, do_h, do_w, a);    // 8 pairs
    else
        seg_body<DPS - 1, true>(s4, base, hoff, do_h, do_w, a); // 7 + plane 127

    // wave (64-lane) shuffle reduction, then LDS across the 4 waves
    float vals[NACC] = { a.cnt_min, a.cnt_max, a.sum_d, a.sum_h,
                         a.sum_w, a.sm, a.sm2, a.les };
    #pragma unroll
    for (int vi = 0; vi < NACC; ++vi) {
        float x = vals[vi];
        #pragma unroll
        for (int offs = 32; offs > 0; offs >>= 1)
            x += __shfl_down(x, offs, 64);
        vals[vi] = x;
    }

    __shared__ float smem[4][NACC];
    const int wave = tid >> 6;
    const int lane = tid & 63;
    if (lane == 0) {
        #pragma unroll
        for (int vi = 0; vi < NACC; ++vi) smem[wave][vi] = vals[vi];
    }
    __syncthreads();
    if (tid < NACC) {
        const int slot = (b << 8) | (seg << 4) | hwblk;
        pacc[(size_t)slot * NACC + tid] =
            smem[0][tid] + smem[1][tid] + smem[2][tid] + smem[3][tid];
    }
}

// One block, 256 threads: thread t handles (batch = t>>4, hwblk j = t&15),
// sums over the 16 segs, then width-16 shuffle-reduces across j.
__global__ __launch_bounds__(THREADS)
void finalize_kernel(const float* __restrict__ pacc, float* __restrict__ out)
{
    const int tid = (int)threadIdx.x;
    const int b   = tid >> 4;
    const int j   = tid & 15;

    double s[NACC];
    #pragma unroll
    for (int i = 0; i < NACC; ++i) s[i] = 0.0;

    const float4* p4 = reinterpret_cast<const float4*>(pacc);
    #pragma unroll
    for (int k = 0; k < DSEGS; ++k) {
        const int slot = (b << 8) | (k << 4) | j;
        const float4 lo = p4[slot * 2];
        const float4 hi = p4[slot * 2 + 1];
        s[0] += lo.x; s[1] += lo.y; s[2] += lo.z; s[3] += lo.w;
        s[4] += hi.x; s[5] += hi.y; s[6] += hi.z; s[7] += hi.w;
    }
    // reduce across the 16 hwblk-lanes (contiguous within the wave)
    #pragma unroll
    for (int i = 0; i < NACC; ++i) {
        #pragma unroll
        for (int offs = 8; offs > 0; offs >>= 1)
            s[i] += __shfl_down(s[i], offs, 16);
    }

    __shared__ float lss[NB];
    if (j == 0) {
        const double cnt    = s[0];
        const double cntmax = s[1];
        const double sd     = s[2];
        const double sh     = s[3];
        const double sw     = s[4];
        const double sm     = s[5];
        const double sm2    = s[6];
        const double les    = s[7];

        const double inv_vox = 1.0 / (double)VOX;
        const double act  = cnt    * inv_vox;
        const double high = cntmax * inv_vox;

        double loss = fmax(0.005 - act, 0.0) * 15.0      // W_MIN
                    + fmax(high - 0.03, 0.0) * 5.0;      // W_MAX

        const double grad_den = 127.0 * 128.0 * 128.0;   // diff-array size
        const double avg_grad = (sd + sh + sw) / (3.0 * grad_den);
        if (les > 0.5)
            loss += fmin(avg_grad, 1.0) * 5.0;           // W_CONT

        const double cnt_safe = fmax(cnt, 1.0);
        const double m  = sm / cnt_safe;
        double sq = sm2 - 2.0 * m * sm + m * m * cnt;
        if (sq < 0.0) sq = 0.0;

        const bool gate = (act > 0.001) && (cnt > 1.0);
        if (gate) {
            const double var     = sq / fmax(cnt - 1.0, 1.0);
            const double rel_std = sqrt(var) / (m + 1e-6);
            loss += exp(-5.0 * rel_std) * 7.0;           // W_SIZE
        }
        lss[b] = (float)loss;
    }
    __syncthreads();
    if (tid == 0) {
        float t = 0.f;
        #pragma unroll
        for (int i = 0; i < NB; ++i) t += lss[i];
        out[0] = t / (float)NB;
    }
}

extern "C" void kernel_launch(void* const* d_in, const int* in_sizes, int n_in,
                              void* d_out, int out_size, void* d_ws, size_t ws_size,
                              hipStream_t stream)
{
    const float* pred = (const float*)d_in[0];
    float* out        = (float*)d_out;
    float* pacc       = (float*)d_ws;   // every slot written every call: no memset

    dim3 grid(DSEGS, HWBLKS, NB);
    partial_kernel<<<grid, THREADS, 0, stream>>>(pred, pacc);
    finalize_kernel<<<1, THREADS, 0, stream>>>(pacc, out);
}